// Round 14
// baseline (6300.523 us; speedup 1.0000x reference)
//
#include <hip/hip_runtime.h>
#include <hip/hip_bf16.h>

typedef __attribute__((ext_vector_type(8))) short short8b;
typedef __attribute__((ext_vector_type(4))) float f32x4;

#define B_   32
#define T_   512
#define I_   1024
#define H_   1024
#define K_   2048          // I + H
#define NB   256           // blocks, each owns 4 H-cols (16 gate cols); 1 wave each
#define NTHR 64            // ONE wave per block; it runs both batch-chains A,B
#define BH   (B_ * H_)
#define HLAST (B_ * H_)
#define TBH ((long)T_ * B_ * H_)
#define SC_SYS __HIP_MEMORY_SCOPE_SYSTEM
#define MAGIC 0x5AB00000u   // flag = MAGIC|t: != 0 (memset) and != 0xAAAAAAAA (poison)
#define SLABSUB 32768       // 256 chunks x 128B per (parity, subset)

__device__ __forceinline__ unsigned short f2bf(float f) {
  union { float f; unsigned u; } c; c.f = f;
  unsigned r = (c.u + 0x7FFFu + ((c.u >> 16) & 1u)) >> 16;  // RNE
  return (unsigned short)r;
}

__device__ __forceinline__ float sig_(float x)  { return 1.0f / (1.0f + __expf(-x)); }
__device__ __forceinline__ float tanh_(float x) { return 1.0f - 2.0f / (__expf(2.0f * x) + 1.0f); }

__device__ __forceinline__ unsigned long long ld64sys(const void* p) {
  return __hip_atomic_load((const unsigned long long*)p, __ATOMIC_RELAXED, SC_SYS);
}

// x [B][T][I] f32  ->  xb [T][B][I] bf16 (step-t slab contiguous)
__global__ void convert_x_kernel(const float* __restrict__ x, unsigned short* __restrict__ xb) {
  long vid = (long)blockIdx.x * blockDim.x + threadIdx.x;
  long o = vid * 4;
  if (o >= (long)T_ * B_ * I_) return;
  int i  = (int)(o & (I_ - 1));
  long bt = o >> 10;
  int b  = (int)(bt & (B_ - 1));
  int t  = (int)(bt >> 5);
  float4 v = *reinterpret_cast<const float4*>(x + (((long)b * T_ + t) << 10) + i);
  ushort4 pk;
  pk.x = f2bf(v.x); pk.y = f2bf(v.y); pk.z = f2bf(v.z); pk.w = f2bf(v.w);
  *reinterpret_cast<ushort4*>(xb + o) = pk;
}

// Persistent LSTM, plain launch (256 blocks x 1 wave, 64 KiB LDS -> 1/CU).
// Batch rows split into 2 INDEPENDENT chains (A=rows 0-15, B=16-31); the wave
// alternates phases so chain X's publish->visibility latency ages under the
// other chain's compute. Transport: parity slab (2 par x 2 sub x 256 x 128B),
// SYSTEM loads (parity reuse forbids cached reads); per-wave flags after a
// vmcnt(0) ack. Slot-reuse safety: flags_X(t) all-set => all waves' X(t-1)
// reads drained (vmcnt precedes flag) => overwrite at t+1 is race-free.
template <bool XBF16>
__global__ __launch_bounds__(NTHR, 1)
void lstm_kernel(const unsigned short* __restrict__ xb, const float* __restrict__ xf,
                 const float* __restrict__ Wf, const float* __restrict__ Wi,
                 const float* __restrict__ Wo, const float* __restrict__ Wc,
                 const float* __restrict__ bfp, const float* __restrict__ bip,
                 const float* __restrict__ bop, const float* __restrict__ bcp,
                 float* __restrict__ out, char* __restrict__ slab,
                 unsigned* __restrict__ flags)
{
  __shared__ unsigned short Wl[16 * 2048];  // 64 KiB weight stripe (bf16, swizzled)
  const int tid = threadIdx.x;
  const int bid = blockIdx.x;
  const int j0  = bid * 4;

  {
    const float* Wg[4] = {Wf, Wi, Wo, Wc};
    for (int g = 0; g < 4; ++g) {
      const float* Wp = Wg[g] + j0;
      for (int k = tid; k < K_; k += NTHR) {
        float4 w = *reinterpret_cast<const float4*>(Wp + (long)k * H_);
        float wv[4] = {w.x, w.y, w.z, w.w};
        #pragma unroll
        for (int cj = 0; cj < 4; ++cj) {
          int n = g * 4 + cj;
          int byteoff = n * 4096 + ((2 * k) ^ ((n & 7) << 4));
          *reinterpret_cast<unsigned short*>(reinterpret_cast<char*>(Wl) + byteoff) = f2bf(wv[cj]);
        }
      }
    }
  }
  __syncthreads();
  __builtin_amdgcn_fence(__ATOMIC_ACQUIRE, "agent");   // purge pre-kernel residue

  const int lane = tid & 63;
  const int lr   = lane & 15;
  const int lg   = lane >> 4;
  const int cj   = lane & 3;

  const float bias_f = bfp[j0 + cj];
  const float bias_i = bip[j0 + cj];
  const float bias_o = bop[j0 + cj];
  const float bias_g = bcp[j0 + cj];

  float creg[2][4] = {{0.f,0.f,0.f,0.f},{0.f,0.f,0.f,0.f}};  // [chain][r]

  const char* WlB   = reinterpret_cast<const char*>(Wl);
  const int colbase = lr * 4096;
  const int swz     = (lr & 7) << 4;

  // x-part GEMM for (t, chain): rows ch*16 + lr
  auto xpart = [&](int t, int ch, f32x4& a0, f32x4& a1) {
    a0 = f32x4{0.f, 0.f, 0.f, 0.f};
    a1 = f32x4{0.f, 0.f, 0.f, 0.f};
    const int row = ch * 16 + lr;
    if (XBF16) {
      const unsigned short* aptr = xb + (((long)(t * B_ + row)) << 10) + lg * 8;
      #pragma unroll
      for (int it = 0; it < 32; ++it) {
        short8b a  = *reinterpret_cast<const short8b*>(aptr + it * 32);
        short8b bb = *reinterpret_cast<const short8b*>(WlB + colbase + ((it * 64 + lg * 16) ^ swz));
        if (it & 1) a1 = __builtin_amdgcn_mfma_f32_16x16x32_bf16(a, bb, a1, 0, 0, 0);
        else        a0 = __builtin_amdgcn_mfma_f32_16x16x32_bf16(a, bb, a0, 0, 0, 0);
      }
    } else {
      const float* aptr = xf + ((long)row * T_ + t) * I_ + lg * 8;
      #pragma unroll
      for (int it = 0; it < 32; ++it) {
        float4 v0 = *reinterpret_cast<const float4*>(aptr + it * 32);
        float4 v1 = *reinterpret_cast<const float4*>(aptr + it * 32 + 4);
        union { __hip_bfloat162 h2[4]; short8b v; } cv;
        cv.h2[0] = __float22bfloat162_rn(float2{v0.x, v0.y});
        cv.h2[1] = __float22bfloat162_rn(float2{v0.z, v0.w});
        cv.h2[2] = __float22bfloat162_rn(float2{v1.x, v1.y});
        cv.h2[3] = __float22bfloat162_rn(float2{v1.z, v1.w});
        short8b bb = *reinterpret_cast<const short8b*>(WlB + colbase + ((it * 64 + lg * 16) ^ swz));
        if (it & 1) a1 = __builtin_amdgcn_mfma_f32_16x16x32_bf16(cv.v, bb, a1, 0, 0, 0);
        else        a0 = __builtin_amdgcn_mfma_f32_16x16x32_bf16(cv.v, bb, a0, 0, 0, 0);
      }
    }
  };

  f32x4 xa[2][2];
  xpart(0, 0, xa[0][0], xa[0][1]);
  xpart(0, 1, xa[1][0], xa[1][1]);

  float hv[2][4];

  for (int t = 0; t < T_; ++t) {
    #pragma unroll
    for (int ch = 0; ch < 2; ++ch) {
      f32x4 a0 = xa[ch][0], a1 = xa[ch][1];

      if (t > 0) {
        // ---- poll this chain's 256 producer flags (2x8B/lane, hot) ----
        const unsigned exp32 = MAGIC | (unsigned)(t - 1);
        const unsigned long long pat =
            ((unsigned long long)exp32 << 32) | (unsigned long long)exp32;
        const unsigned long long* fb = reinterpret_cast<const unsigned long long*>(
            flags + (((t - 1) & 1) * 2 + ch) * 256) + lane * 2;
        while (true) {
          unsigned long long f0 = ld64sys(fb);
          unsigned long long f1 = ld64sys(fb + 1);
          if (__all((f0 == pat) & (f1 == pat))) break;
        }
        asm volatile("" ::: "memory");

        // ---- h-part GEMM: system 8B loads from parity slab ----
        const char* hb = slab + (((t - 1) & 1) * 2 + ch) * SLABSUB + lr * 8 + lg * 256;
        unsigned long long u0[8][2], u1[8][2];
        auto issue = [&](int g, unsigned long long (&u)[8][2]) {
          #pragma unroll
          for (int f = 0; f < 8; ++f) {
            const char* p = hb + ((g * 8 + f) * 8) * 128;   // chunk pid = kt*8 + lg*2
            u[f][0] = ld64sys(p);
            u[f][1] = ld64sys(p + 128);
          }
        };
        auto domfma = [&](int g, unsigned long long (&u)[8][2]) {
          #pragma unroll
          for (int f = 0; f < 8; ++f) {
            const int it = g * 8 + f;
            union { unsigned long long q[2]; short8b v; } cv;
            cv.q[0] = u[f][0]; cv.q[1] = u[f][1];
            short8b bb = *reinterpret_cast<const short8b*>(
                WlB + colbase + ((2048 + it * 64 + lg * 16) ^ swz));
            if (it & 1) a1 = __builtin_amdgcn_mfma_f32_16x16x32_bf16(cv.v, bb, a1, 0, 0, 0);
            else        a0 = __builtin_amdgcn_mfma_f32_16x16x32_bf16(cv.v, bb, a0, 0, 0, 0);
          }
        };
        issue(0, u0);
        issue(1, u1);
        domfma(0, u0); issue(2, u0);
        domfma(1, u1); issue(3, u1);
        domfma(2, u0);
        domfma(3, u1);
      }

      f32x4 acc = a0 + a1;

      // ---- gates: D[row=lg*4+r][col=lr]; lane wants cols g*4+cj ----
      float gate[4][4];
      #pragma unroll
      for (int g = 0; g < 4; ++g) {
        const int src = lg * 16 + g * 4 + cj;
        #pragma unroll
        for (int r = 0; r < 4; ++r) gate[g][r] = __shfl(acc[r], src, 64);
      }
      #pragma unroll
      for (int r = 0; r < 4; ++r) {
        float fg = sig_(gate[0][r] + bias_f);
        float ig = sig_(gate[1][r] + bias_i);
        float og = sig_(gate[2][r] + bias_o);
        float gg = tanh_(gate[3][r] + bias_g);
        float c  = fg * creg[ch][r] + ig * gg;
        creg[ch][r] = c;
        hv[ch][r]   = og * tanh_(c);
      }

      if (t < T_ - 1) {
        // ---- publish chunk (128B/wave, 2B/lane system stores) ----
        const int src = ((lane >> 4) << 4) | (lane & 3);
        float hr0 = __shfl(hv[ch][0], src, 64);
        float hr1 = __shfl(hv[ch][1], src, 64);
        float hr2 = __shfl(hv[ch][2], src, 64);
        float hr3 = __shfl(hv[ch][3], src, 64);
        const int rsel = (lane >> 2) & 3;
        float v = (rsel == 0) ? hr0 : (rsel == 1) ? hr1 : (rsel == 2) ? hr2 : hr3;
        __hip_atomic_store(
            reinterpret_cast<unsigned short*>(
                slab + ((t & 1) * 2 + ch) * SLABSUB + bid * 128 + lane * 2),
            f2bf(v), __ATOMIC_RELAXED, SC_SYS);

        // next-step x-part fills the ack window (its cached loads drain fast)
        xpart(t + 1, ch, xa[ch][0], xa[ch][1]);

        asm volatile("s_waitcnt vmcnt(0)" ::: "memory");   // chunk + reads drained
        if (lane == 0)
          __hip_atomic_store(&flags[((t & 1) * 2 + ch) * 256 + bid],
                             MAGIC | (unsigned)t, __ATOMIC_RELAXED, SC_SYS);
      }
    }

    // ---- output stores for both chains (plain f32, off critical path) ----
    if ((lane & 12) == 0) {
      #pragma unroll
      for (int ch = 0; ch < 2; ++ch) {
        #pragma unroll
        for (int r = 0; r < 4; ++r) {
          const int row  = ch * 16 + lg * 4 + r;
          const int colj = j0 + cj;
          const long oh  = (long)(t * B_ + row) * H_ + colj;
          out[HLAST + oh]       = hv[ch][r];
          out[HLAST + TBH + oh] = creg[ch][r];
          if (t == T_ - 1) out[(long)row * H_ + colj] = hv[ch][r];
        }
      }
    }
  }
}

// Fallback (ws too small): per-step kernel gathering raw f32 each step.
__global__ void lstm_step_fallback_kernel(int t,
    const float* __restrict__ xf,
    const float* __restrict__ Wf, const float* __restrict__ Wi,
    const float* __restrict__ Wo, const float* __restrict__ Wc,
    const float* __restrict__ bfp, const float* __restrict__ bip,
    const float* __restrict__ bop, const float* __restrict__ bcp,
    float* __restrict__ out, unsigned short* __restrict__ hbuf)
{
  const int tid  = threadIdx.x;
  const int bid  = blockIdx.x;
  const int lane = tid & 63;
  const int m    = tid >> 6;
  const int lr   = lane & 15;
  const int lg   = lane >> 4;
  const int b    = m * 16 + lr;
  const int cj   = lane & 3;
  const int j0   = bid * 4;
  const int gb0  = m * 16 + lg * 4;

  const unsigned short* hcur = hbuf + (t & 1) * BH;
  f32x4 a0 = {0.f, 0.f, 0.f, 0.f};
  f32x4 a1 = {0.f, 0.f, 0.f, 0.f};

  const int g    = lr >> 2;
  const int colg = j0 + (lr & 3);
  const float* Wg = (g == 0) ? Wf : (g == 1) ? Wi : (g == 2) ? Wo : Wc;
  const float* axf = xf + ((long)b * T_ + t) * I_ + lg * 8;
  const unsigned short* ah = hcur + (b << 10) + lg * 8;
  #pragma unroll 4
  for (int it = 0; it < 32; ++it) {
    const int k0 = it * 32 + lg * 8;
    short8b a, bb;
    #pragma unroll
    for (int e = 0; e < 8; ++e) {
      a[e]  = (short)f2bf(axf[it * 32 + e]);
      bb[e] = (short)f2bf(Wg[(size_t)(k0 + e) * H_ + colg]);
    }
    if (it & 1) a1 = __builtin_amdgcn_mfma_f32_16x16x32_bf16(a, bb, a1, 0, 0, 0);
    else        a0 = __builtin_amdgcn_mfma_f32_16x16x32_bf16(a, bb, a0, 0, 0, 0);
  }
  #pragma unroll 4
  for (int it = 0; it < 32; ++it) {
    const int k0 = 1024 + it * 32 + lg * 8;
    short8b a = *reinterpret_cast<const short8b*>(ah + it * 32);
    short8b bb;
    #pragma unroll
    for (int e = 0; e < 8; ++e)
      bb[e] = (short)f2bf(Wg[(size_t)(k0 + e) * H_ + colg]);
    if (it & 1) a1 = __builtin_amdgcn_mfma_f32_16x16x32_bf16(a, bb, a1, 0, 0, 0);
    else        a0 = __builtin_amdgcn_mfma_f32_16x16x32_bf16(a, bb, a0, 0, 0, 0);
  }
  f32x4 acc = a0 + a1;

  float gate[4][4];
  #pragma unroll
  for (int gg = 0; gg < 4; ++gg) {
    const int src = lg * 16 + gg * 4 + cj;
    #pragma unroll
    for (int r = 0; r < 4; ++r) gate[gg][r] = __shfl(acc[r], src, 64);
  }

  if ((lane & 12) == 0) {
    const int col = j0 + cj;
    const float bias_f = bfp[col];
    const float bias_i = bip[col];
    const float bias_o = bop[col];
    const float bias_g = bcp[col];
    #pragma unroll
    for (int r = 0; r < 4; ++r) {
      const int row = gb0 + r;
      float cp = (t == 0) ? 0.f
               : out[HLAST + TBH + (long)((t - 1) * B_ + row) * H_ + col];
      float fg = sig_(gate[0][r] + bias_f);
      float ig = sig_(gate[1][r] + bias_i);
      float og = sig_(gate[2][r] + bias_o);
      float gv = tanh_(gate[3][r] + bias_g);
      float c  = fg * cp + ig * gv;
      float hv = og * tanh_(c);
      const long oh = (long)(t * B_ + row) * H_ + col;
      out[HLAST + oh]       = hv;
      out[HLAST + TBH + oh] = c;
      hbuf[((t + 1) & 1) * BH + row * H_ + col] = f2bf(hv);
      if (t == T_ - 1) out[(long)row * H_ + col] = hv;
    }
  }
}

extern "C" void kernel_launch(void* const* d_in, const int* in_sizes, int n_in,
                              void* d_out, int out_size, void* d_ws, size_t ws_size,
                              hipStream_t stream) {
  const float* x   = (const float*)d_in[0];
  const float* Wf  = (const float*)d_in[1];
  const float* bf_ = (const float*)d_in[2];
  const float* Wi  = (const float*)d_in[3];
  const float* bi_ = (const float*)d_in[4];
  const float* Wo  = (const float*)d_in[5];
  const float* bo_ = (const float*)d_in[6];
  const float* Wc  = (const float*)d_in[7];
  const float* bc_ = (const float*)d_in[8];
  float* out = (float*)d_out;

  const size_t slab_bytes  = (size_t)4 * SLABSUB;         // 128 KiB parity slab
  const size_t flags_bytes = (size_t)4 * 256 * 4;         // 4 KiB flags
  const size_t xb_bytes    = (size_t)T_ * B_ * I_ * 2;    // 32 MiB
  const bool has_slab = ws_size >= slab_bytes + flags_bytes;
  const bool has_xb   = ws_size >= slab_bytes + flags_bytes + xb_bytes;

  if (has_slab) {
    char* slab         = (char*)d_ws;
    unsigned* flags    = (unsigned*)((char*)d_ws + slab_bytes);
    unsigned short* xb = (unsigned short*)((char*)d_ws + slab_bytes + flags_bytes);

    // flags must be call-fresh (parity slots are gated by exact MAGIC|t values)
    (void)hipMemsetAsync(flags, 0, flags_bytes, stream);

    if (has_xb) {
      const int total_vec = T_ * B_ * I_ / 4;
      convert_x_kernel<<<dim3(total_vec / 256), dim3(256), 0, stream>>>(x, xb);
      lstm_kernel<true><<<dim3(NB), dim3(NTHR), 0, stream>>>(
          xb, x, Wf, Wi, Wo, Wc, bf_, bi_, bo_, bc_, out, slab, flags);
    } else {
      lstm_kernel<false><<<dim3(NB), dim3(NTHR), 0, stream>>>(
          xb, x, Wf, Wi, Wo, Wc, bf_, bi_, bo_, bc_, out, slab, flags);
    }
  } else {
    unsigned short* hbuf = (unsigned short*)d_ws;
    (void)hipMemsetAsync(hbuf, 0, (size_t)2 * BH * 2, stream);
    for (int t = 0; t < T_; ++t)
      lstm_step_fallback_kernel<<<dim3(NB), dim3(128), 0, stream>>>(
          t, x, Wf, Wi, Wo, Wc, bf_, bi_, bo_, bc_, out, hbuf);
  }
}

// Round 15
// 3419.550 us; speedup vs baseline: 1.8425x; 1.8425x over previous
//
#include <hip/hip_runtime.h>
#include <hip/hip_bf16.h>

typedef __attribute__((ext_vector_type(8))) short short8b;
typedef __attribute__((ext_vector_type(4))) float f32x4;

#define B_   32
#define T_   512
#define I_   1024
#define H_   1024
#define K_   2048          // I + H
#define NB   256           // blocks, each owns 4 H-cols (16 gate cols); 1 per CU
#define NTHR 128           // 2 waves: wave m handles batch rows m*16..m*16+15
#define BH   (B_ * H_)
#define HLAST (B_ * H_)
#define TBH ((long)T_ * B_ * H_)
#define SC_SYS __HIP_MEMORY_SCOPE_SYSTEM
#define MAGIC 0x5AB00000u   // flag = MAGIC|t: != 0 (memset) and != 0xAAAAAAAA (poison)

__device__ __forceinline__ unsigned short f2bf(float f) {
  union { float f; unsigned u; } c; c.f = f;
  unsigned r = (c.u + 0x7FFFu + ((c.u >> 16) & 1u)) >> 16;  // RNE
  return (unsigned short)r;
}

__device__ __forceinline__ float sig_(float x)  { return 1.0f / (1.0f + __expf(-x)); }
__device__ __forceinline__ float tanh_(float x) { return 1.0f - 2.0f / (__expf(2.0f * x) + 1.0f); }

__device__ __forceinline__ unsigned long long ld64sys(const void* p) {
  return __hip_atomic_load((const unsigned long long*)p, __ATOMIC_RELAXED, SC_SYS);
}

// x [B][T][I] f32  ->  xb [T][B][I] bf16 (step-t slab contiguous)
__global__ void convert_x_kernel(const float* __restrict__ x, unsigned short* __restrict__ xb) {
  long vid = (long)blockIdx.x * blockDim.x + threadIdx.x;
  long o = vid * 4;
  if (o >= (long)T_ * B_ * I_) return;
  int i  = (int)(o & (I_ - 1));
  long bt = o >> 10;
  int b  = (int)(bt & (B_ - 1));
  int t  = (int)(bt >> 5);
  float4 v = *reinterpret_cast<const float4*>(x + (((long)b * T_ + t) << 10) + i);
  ushort4 pk;
  pk.x = f2bf(v.x); pk.y = f2bf(v.y); pk.z = f2bf(v.z); pk.w = f2bf(v.w);
  *reinterpret_cast<ushort4*>(xb + o) = pk;
}

// Persistent LSTM, plain launch (256 x 128, 64 KiB LDS -> 1 block/CU).
// r13 structure (single rendezvous/step, two waves = two parallel M-halves)
// with ONE change: the publish-ack is AGED under xpart(t+1) -- order is
// chunk store -> xpart -> vmcnt(0) -> flag -> out stores. The compiler's
// internal waits for xpart's loads (issued after the chunk; vmcnt retires
// in-order) mean the chunk is complete by xpart's end, so the explicit
// vmcnt(0) is ~free and the ack round-trip hides under real work.
template <bool XBF16>
__global__ __launch_bounds__(NTHR, 1)
void lstm_kernel(const unsigned short* __restrict__ xb, const float* __restrict__ xf,
                 const float* __restrict__ Wf, const float* __restrict__ Wi,
                 const float* __restrict__ Wo, const float* __restrict__ Wc,
                 const float* __restrict__ bfp, const float* __restrict__ bip,
                 const float* __restrict__ bop, const float* __restrict__ bcp,
                 float* __restrict__ out, char* __restrict__ hseqp,
                 unsigned* __restrict__ flags)
{
  __shared__ unsigned short Wl[16 * 2048];  // 64 KiB weight stripe (bf16, swizzled)
  const int tid = threadIdx.x;
  const int bid = blockIdx.x;
  const int j0  = bid * 4;

  {
    const float* Wg[4] = {Wf, Wi, Wo, Wc};
    for (int g = 0; g < 4; ++g) {
      const float* Wp = Wg[g] + j0;
      for (int k = tid; k < K_; k += NTHR) {
        float4 w = *reinterpret_cast<const float4*>(Wp + (long)k * H_);
        float wv[4] = {w.x, w.y, w.z, w.w};
        #pragma unroll
        for (int cj = 0; cj < 4; ++cj) {
          int n = g * 4 + cj;
          int byteoff = n * 4096 + ((2 * k) ^ ((n & 7) << 4));
          *reinterpret_cast<unsigned short*>(reinterpret_cast<char*>(Wl) + byteoff) = f2bf(wv[cj]);
        }
      }
    }
  }
  __syncthreads();

  // Purge pre-kernel L1/L2 residue once; after this, hseqp lines enter caches
  // only via our own post-flag reads.
  __builtin_amdgcn_fence(__ATOMIC_ACQUIRE, "agent");

  const int lane = tid & 63;
  const int m    = tid >> 6;
  const int lr   = lane & 15;
  const int lg   = lane >> 4;
  const int b    = m * 16 + lr;     // batch row fed into A-fragment
  const int cj   = lane & 3;        // H-column (within block) this lane gates
  const int gb0  = m * 16 + lg * 4; // first batch row this lane gates

  const float bias_f = bfp[j0 + cj];
  const float bias_i = bip[j0 + cj];
  const float bias_o = bop[j0 + cj];
  const float bias_g = bcp[j0 + cj];

  float creg[4] = {0.f, 0.f, 0.f, 0.f};  // c state in registers for all T steps

  const char* WlB   = reinterpret_cast<const char*>(Wl);
  const int colbase = lr * 4096;
  const int swz     = (lr & 7) << 4;

  // x-part GEMM for step t (ages the publish-ack when called post-store)
  auto xpart = [&](int t, f32x4& a0, f32x4& a1) {
    a0 = f32x4{0.f, 0.f, 0.f, 0.f};
    a1 = f32x4{0.f, 0.f, 0.f, 0.f};
    if (XBF16) {
      const unsigned short* aptr = xb + (((long)(t * B_ + b)) << 10) + lg * 8;
      #pragma unroll
      for (int it = 0; it < 32; ++it) {
        short8b a  = *reinterpret_cast<const short8b*>(aptr + it * 32);
        short8b bb = *reinterpret_cast<const short8b*>(WlB + colbase + ((it * 64 + lg * 16) ^ swz));
        if (it & 1) a1 = __builtin_amdgcn_mfma_f32_16x16x32_bf16(a, bb, a1, 0, 0, 0);
        else        a0 = __builtin_amdgcn_mfma_f32_16x16x32_bf16(a, bb, a0, 0, 0, 0);
      }
    } else {
      const float* aptr = xf + ((long)b * T_ + t) * I_ + lg * 8;
      #pragma unroll
      for (int it = 0; it < 32; ++it) {
        float4 v0 = *reinterpret_cast<const float4*>(aptr + it * 32);
        float4 v1 = *reinterpret_cast<const float4*>(aptr + it * 32 + 4);
        union { __hip_bfloat162 h2[4]; short8b v; } cv;
        cv.h2[0] = __float22bfloat162_rn(float2{v0.x, v0.y});
        cv.h2[1] = __float22bfloat162_rn(float2{v0.z, v0.w});
        cv.h2[2] = __float22bfloat162_rn(float2{v1.x, v1.y});
        cv.h2[3] = __float22bfloat162_rn(float2{v1.z, v1.w});
        short8b bb = *reinterpret_cast<const short8b*>(WlB + colbase + ((it * 64 + lg * 16) ^ swz));
        if (it & 1) a1 = __builtin_amdgcn_mfma_f32_16x16x32_bf16(cv.v, bb, a1, 0, 0, 0);
        else        a0 = __builtin_amdgcn_mfma_f32_16x16x32_bf16(cv.v, bb, a0, 0, 0, 0);
      }
    }
  };

  f32x4 xa0, xa1;
  xpart(0, xa0, xa1);

  for (int t = 0; t < T_; ++t) {
    f32x4 a0 = xa0, a1 = xa1;

    if (t > 0) {
      // ---- both waves poll all 512 per-wave flags (4x8B/lane, parallel issue) ----
      {
        const unsigned exp32 = MAGIC | (unsigned)(t - 1);
        const unsigned long long pat =
            ((unsigned long long)exp32 << 32) | (unsigned long long)exp32;
        const unsigned long long* fb =
            reinterpret_cast<const unsigned long long*>(flags + (long)(t - 1) * 512) + lane * 4;
        while (true) {
          unsigned long long f0 = ld64sys(fb);
          unsigned long long f1 = ld64sys(fb + 1);
          unsigned long long f2 = ld64sys(fb + 2);
          unsigned long long f3 = ld64sys(fb + 3);
          if (__all((f0 == pat) & (f1 == pat) & (f2 == pat) & (f3 == pat))) break;
        }
      }
      asm volatile("" ::: "memory");   // no cached h loads hoisted above the poll

      // ---- h-part GEMM: plain cached 8B loads from packed chunks ----
      const char* hb = hseqp + ((long)(t - 1) << 16) + m * 128 + lr * 8 + lg * 512;
      unsigned long long u0[8][2], u1[8][2];
      auto issue = [&](int g, unsigned long long (&u)[8][2]) {
        #pragma unroll
        for (int f = 0; f < 8; ++f) {
          const char* p = hb + ((g * 8 + f) * 8) * 256;   // chunk j = it*8 + lg*2
          u[f][0] = *reinterpret_cast<const unsigned long long*>(p);
          u[f][1] = *reinterpret_cast<const unsigned long long*>(p + 256);
        }
      };
      auto domfma = [&](int g, unsigned long long (&u)[8][2]) {
        #pragma unroll
        for (int f = 0; f < 8; ++f) {
          const int it = g * 8 + f;
          union { unsigned long long q[2]; short8b v; } cv;
          cv.q[0] = u[f][0]; cv.q[1] = u[f][1];
          short8b bb = *reinterpret_cast<const short8b*>(
              WlB + colbase + ((2048 + it * 64 + lg * 16) ^ swz));
          if (it & 1) a1 = __builtin_amdgcn_mfma_f32_16x16x32_bf16(cv.v, bb, a1, 0, 0, 0);
          else        a0 = __builtin_amdgcn_mfma_f32_16x16x32_bf16(cv.v, bb, a0, 0, 0, 0);
        }
      };
      issue(0, u0);
      issue(1, u1);
      domfma(0, u0); issue(2, u0);
      domfma(1, u1); issue(3, u1);
      domfma(2, u0);
      domfma(3, u1);
    }

    f32x4 acc = a0 + a1;

    // ---- gates: D[row=lg*4+r][col=lr]; lane wants cols g*4+cj ----
    float gate[4][4];
    #pragma unroll
    for (int g = 0; g < 4; ++g) {
      const int src = lg * 16 + g * 4 + cj;
      #pragma unroll
      for (int r = 0; r < 4; ++r) gate[g][r] = __shfl(acc[r], src, 64);
    }

    float hv[4];
    #pragma unroll
    for (int r = 0; r < 4; ++r) {
      float fg = sig_(gate[0][r] + bias_f);
      float ig = sig_(gate[1][r] + bias_i);
      float og = sig_(gate[2][r] + bias_o);
      float gg = tanh_(gate[3][r] + bias_g);
      float c  = fg * creg[r] + ig * gg;
      creg[r]  = c;
      hv[r]    = og * tanh_(c);
    }

    if (t < T_ - 1) {
      // ---- publish chunk (1 coalesced 128B store/wave) ----
      const int src = ((lane >> 4) << 4) | (lane & 3);   // source lane for (row,col)
      float hr0 = __shfl(hv[0], src, 64);
      float hr1 = __shfl(hv[1], src, 64);
      float hr2 = __shfl(hv[2], src, 64);
      float hr3 = __shfl(hv[3], src, 64);
      const int rsel = (lane >> 2) & 3;
      float v = (rsel == 0) ? hr0 : (rsel == 1) ? hr1 : (rsel == 2) ? hr2 : hr3;
      unsigned short hs = f2bf(v);
      __hip_atomic_store(
          reinterpret_cast<unsigned short*>(hseqp + ((long)t << 16) + bid * 256 + m * 128 + lane * 2),
          hs, __ATOMIC_RELAXED, SC_SYS);

      // ---- age the ack: next-step x-GEMM runs while the chunk is in flight ----
      xpart(t + 1, xa0, xa1);

      // by now the chunk (oldest vmem) has effectively completed; this wait is ~free
      asm volatile("s_waitcnt vmcnt(0)" ::: "memory");
      if (lane == 0)
        __hip_atomic_store(&flags[(long)t * 512 + bid * 2 + m], MAGIC | (unsigned)t,
                           __ATOMIC_RELAXED, SC_SYS);

      // ---- h/c output stores drain in the rendezvous shadow ----
      if ((lane & 12) == 0) {
        #pragma unroll
        for (int r = 0; r < 4; ++r) {
          const long oh = (long)(t * B_ + gb0 + r) * H_ + j0 + cj;
          out[HLAST + oh]       = hv[r];
          out[HLAST + TBH + oh] = creg[r];
        }
      }
    } else {
      if ((lane & 12) == 0) {
        #pragma unroll
        for (int r = 0; r < 4; ++r) {
          const int row  = gb0 + r;
          const int colj = j0 + cj;
          const long oh  = (long)(t * B_ + row) * H_ + colj;
          out[HLAST + oh]        = hv[r];
          out[HLAST + TBH + oh]  = creg[r];
          out[(long)row * H_ + colj] = hv[r];
        }
      }
    }
  }
}

// Fallback (ws too small): per-step kernel gathering raw f32 each step.
__global__ void lstm_step_fallback_kernel(int t,
    const float* __restrict__ xf,
    const float* __restrict__ Wf, const float* __restrict__ Wi,
    const float* __restrict__ Wo, const float* __restrict__ Wc,
    const float* __restrict__ bfp, const float* __restrict__ bip,
    const float* __restrict__ bop, const float* __restrict__ bcp,
    float* __restrict__ out, unsigned short* __restrict__ hbuf)
{
  const int tid  = threadIdx.x;
  const int bid  = blockIdx.x;
  const int lane = tid & 63;
  const int m    = tid >> 6;
  const int lr   = lane & 15;
  const int lg   = lane >> 4;
  const int b    = m * 16 + lr;
  const int cj   = lane & 3;
  const int j0   = bid * 4;
  const int gb0  = m * 16 + lg * 4;

  const unsigned short* hcur = hbuf + (t & 1) * BH;
  f32x4 a0 = {0.f, 0.f, 0.f, 0.f};
  f32x4 a1 = {0.f, 0.f, 0.f, 0.f};

  const int g    = lr >> 2;
  const int colg = j0 + (lr & 3);
  const float* Wg = (g == 0) ? Wf : (g == 1) ? Wi : (g == 2) ? Wo : Wc;
  const float* axf = xf + ((long)b * T_ + t) * I_ + lg * 8;
  const unsigned short* ah = hcur + (b << 10) + lg * 8;
  #pragma unroll 4
  for (int it = 0; it < 32; ++it) {
    const int k0 = it * 32 + lg * 8;
    short8b a, bb;
    #pragma unroll
    for (int e = 0; e < 8; ++e) {
      a[e]  = (short)f2bf(axf[it * 32 + e]);
      bb[e] = (short)f2bf(Wg[(size_t)(k0 + e) * H_ + colg]);
    }
    if (it & 1) a1 = __builtin_amdgcn_mfma_f32_16x16x32_bf16(a, bb, a1, 0, 0, 0);
    else        a0 = __builtin_amdgcn_mfma_f32_16x16x32_bf16(a, bb, a0, 0, 0, 0);
  }
  #pragma unroll 4
  for (int it = 0; it < 32; ++it) {
    const int k0 = 1024 + it * 32 + lg * 8;
    short8b a = *reinterpret_cast<const short8b*>(ah + it * 32);
    short8b bb;
    #pragma unroll
    for (int e = 0; e < 8; ++e)
      bb[e] = (short)f2bf(Wg[(size_t)(k0 + e) * H_ + colg]);
    if (it & 1) a1 = __builtin_amdgcn_mfma_f32_16x16x32_bf16(a, bb, a1, 0, 0, 0);
    else        a0 = __builtin_amdgcn_mfma_f32_16x16x32_bf16(a, bb, a0, 0, 0, 0);
  }
  f32x4 acc = a0 + a1;

  float gate[4][4];
  #pragma unroll
  for (int gg = 0; gg < 4; ++gg) {
    const int src = lg * 16 + gg * 4 + cj;
    #pragma unroll
    for (int r = 0; r < 4; ++r) gate[gg][r] = __shfl(acc[r], src, 64);
  }

  if ((lane & 12) == 0) {
    const int col = j0 + cj;
    const float bias_f = bfp[col];
    const float bias_i = bip[col];
    const float bias_o = bop[col];
    const float bias_g = bcp[col];
    #pragma unroll
    for (int r = 0; r < 4; ++r) {
      const int row = gb0 + r;
      float cp = (t == 0) ? 0.f
               : out[HLAST + TBH + (long)((t - 1) * B_ + row) * H_ + col];
      float fg = sig_(gate[0][r] + bias_f);
      float ig = sig_(gate[1][r] + bias_i);
      float og = sig_(gate[2][r] + bias_o);
      float gv = tanh_(gate[3][r] + bias_g);
      float c  = fg * cp + ig * gv;
      float hv = og * tanh_(c);
      const long oh = (long)(t * B_ + row) * H_ + col;
      out[HLAST + oh]       = hv;
      out[HLAST + TBH + oh] = c;
      hbuf[((t + 1) & 1) * BH + row * H_ + col] = f2bf(hv);
      if (t == T_ - 1) out[(long)row * H_ + col] = hv;
    }
  }
}

extern "C" void kernel_launch(void* const* d_in, const int* in_sizes, int n_in,
                              void* d_out, int out_size, void* d_ws, size_t ws_size,
                              hipStream_t stream) {
  const float* x   = (const float*)d_in[0];
  const float* Wf  = (const float*)d_in[1];
  const float* bf_ = (const float*)d_in[2];
  const float* Wi  = (const float*)d_in[3];
  const float* bi_ = (const float*)d_in[4];
  const float* Wo  = (const float*)d_in[5];
  const float* bo_ = (const float*)d_in[6];
  const float* Wc  = (const float*)d_in[7];
  const float* bc_ = (const float*)d_in[8];
  float* out = (float*)d_out;

  const size_t hseq_bytes  = (size_t)T_ * 65536;          // 32 MiB packed chunks
  const size_t flags_bytes = (size_t)T_ * 512 * 4;        // 1 MiB per-wave flags
  const size_t xb_bytes    = (size_t)T_ * B_ * I_ * 2;    // 32 MiB
  const bool has_hseq = ws_size >= hseq_bytes + flags_bytes;
  const bool has_xb   = ws_size >= hseq_bytes + flags_bytes + xb_bytes;

  if (has_hseq) {
    char* hseqp        = (char*)d_ws;
    unsigned* flags    = (unsigned*)((char*)d_ws + hseq_bytes);
    unsigned short* xb = (unsigned short*)((char*)d_ws + hseq_bytes + flags_bytes);

    // only flags need re-arming each call (graph-replay safe); hseqp content
    // is gated by flags so its initial bytes are irrelevant.
    (void)hipMemsetAsync(flags, 0, flags_bytes, stream);

    if (has_xb) {
      const int total_vec = T_ * B_ * I_ / 4;
      convert_x_kernel<<<dim3(total_vec / 256), dim3(256), 0, stream>>>(x, xb);
      lstm_kernel<true><<<dim3(NB), dim3(NTHR), 0, stream>>>(
          xb, x, Wf, Wi, Wo, Wc, bf_, bi_, bo_, bc_, out, hseqp, flags);
    } else {
      lstm_kernel<false><<<dim3(NB), dim3(NTHR), 0, stream>>>(
          xb, x, Wf, Wi, Wo, Wc, bf_, bi_, bo_, bc_, out, hseqp, flags);
    }
  } else {
    unsigned short* hbuf = (unsigned short*)d_ws;
    (void)hipMemsetAsync(hbuf, 0, (size_t)2 * BH * 2, stream);
    for (int t = 0; t < T_; ++t)
      lstm_step_fallback_kernel<<<dim3(NB), dim3(128), 0, stream>>>(
          t, x, Wf, Wi, Wo, Wc, bf_, bi_, bo_, bc_, out, hbuf);
  }
}

// Round 16
// 2919.869 us; speedup vs baseline: 2.1578x; 1.1711x over previous
//
#include <hip/hip_runtime.h>
#include <hip/hip_bf16.h>

typedef __attribute__((ext_vector_type(8))) short short8b;
typedef __attribute__((ext_vector_type(4))) float f32x4;

#define B_   32
#define T_   512
#define I_   1024
#define H_   1024
#define K_   2048          // I + H
#define NB   256           // blocks, each owns 4 H-cols (16 gate cols); 1 per CU
#define NTHR 128           // 2 waves: wave m handles batch rows m*16..m*16+15
#define BH   (B_ * H_)
#define HLAST (B_ * H_)
#define TBH ((long)T_ * B_ * H_)
#define SC_SYS __HIP_MEMORY_SCOPE_SYSTEM
#define MAGIC 0x5AB00000u   // flag = MAGIC|t: != 0 (memset) and != 0xAAAAAAAA (poison)

__device__ __forceinline__ unsigned short f2bf(float f) {
  union { float f; unsigned u; } c; c.f = f;
  unsigned r = (c.u + 0x7FFFu + ((c.u >> 16) & 1u)) >> 16;  // RNE
  return (unsigned short)r;
}

__device__ __forceinline__ float sig_(float x)  { return 1.0f / (1.0f + __expf(-x)); }
__device__ __forceinline__ float tanh_(float x) { return 1.0f - 2.0f / (__expf(2.0f * x) + 1.0f); }

__device__ __forceinline__ unsigned long long ld64sys(const void* p) {
  return __hip_atomic_load((const unsigned long long*)p, __ATOMIC_RELAXED, SC_SYS);
}

// x [B][T][I] f32  ->  xb [T][B][I] bf16 (step-t slab contiguous)
__global__ void convert_x_kernel(const float* __restrict__ x, unsigned short* __restrict__ xb) {
  long vid = (long)blockIdx.x * blockDim.x + threadIdx.x;
  long o = vid * 4;
  if (o >= (long)T_ * B_ * I_) return;
  int i  = (int)(o & (I_ - 1));
  long bt = o >> 10;
  int b  = (int)(bt & (B_ - 1));
  int t  = (int)(bt >> 5);
  float4 v = *reinterpret_cast<const float4*>(x + (((long)b * T_ + t) << 10) + i);
  ushort4 pk;
  pk.x = f2bf(v.x); pk.y = f2bf(v.y); pk.z = f2bf(v.z); pk.w = f2bf(v.w);
  *reinterpret_cast<ushort4*>(xb + o) = pk;
}

// Persistent LSTM, plain launch (256 x 128, 64 KiB LDS -> 1 block/CU).
// r13 structure with ONE change: the two waves are fully independent batch
// chains (wave m's h-GEMM reads only rows m*16..+15 = wave-m chunk halves),
// so flags are reorganized [t][m][256] and wave m polls ONLY its own 256 --
// halving the skew population and poll footprint, and letting the CU overlap
// one wave's spin with the other's compute. Publish ordering is r13's proven
// one: chunk store -> vmcnt(0) -> flag -> outs -> xpart (flag ASAP).
template <bool XBF16>
__global__ __launch_bounds__(NTHR, 1)
void lstm_kernel(const unsigned short* __restrict__ xb, const float* __restrict__ xf,
                 const float* __restrict__ Wf, const float* __restrict__ Wi,
                 const float* __restrict__ Wo, const float* __restrict__ Wc,
                 const float* __restrict__ bfp, const float* __restrict__ bip,
                 const float* __restrict__ bop, const float* __restrict__ bcp,
                 float* __restrict__ out, char* __restrict__ hseqp,
                 unsigned* __restrict__ flags)
{
  __shared__ unsigned short Wl[16 * 2048];  // 64 KiB weight stripe (bf16, swizzled)
  const int tid = threadIdx.x;
  const int bid = blockIdx.x;
  const int j0  = bid * 4;

  {
    const float* Wg[4] = {Wf, Wi, Wo, Wc};
    for (int g = 0; g < 4; ++g) {
      const float* Wp = Wg[g] + j0;
      for (int k = tid; k < K_; k += NTHR) {
        float4 w = *reinterpret_cast<const float4*>(Wp + (long)k * H_);
        float wv[4] = {w.x, w.y, w.z, w.w};
        #pragma unroll
        for (int cj = 0; cj < 4; ++cj) {
          int n = g * 4 + cj;
          int byteoff = n * 4096 + ((2 * k) ^ ((n & 7) << 4));
          *reinterpret_cast<unsigned short*>(reinterpret_cast<char*>(Wl) + byteoff) = f2bf(wv[cj]);
        }
      }
    }
  }
  __syncthreads();

  // Purge pre-kernel L1/L2 residue once; after this, hseqp lines enter caches
  // only via our own post-flag reads.
  __builtin_amdgcn_fence(__ATOMIC_ACQUIRE, "agent");

  const int lane = tid & 63;
  const int m    = tid >> 6;
  const int lr   = lane & 15;
  const int lg   = lane >> 4;
  const int b    = m * 16 + lr;     // batch row fed into A-fragment
  const int cj   = lane & 3;        // H-column (within block) this lane gates
  const int gb0  = m * 16 + lg * 4; // first batch row this lane gates

  const float bias_f = bfp[j0 + cj];
  const float bias_i = bip[j0 + cj];
  const float bias_o = bop[j0 + cj];
  const float bias_g = bcp[j0 + cj];

  float creg[4] = {0.f, 0.f, 0.f, 0.f};  // c state in registers for all T steps

  const char* WlB   = reinterpret_cast<const char*>(Wl);
  const int colbase = lr * 4096;
  const int swz     = (lr & 7) << 4;

  // x-part GEMM for step t (off critical path; runs in rendezvous shadow)
  auto xpart = [&](int t, f32x4& a0, f32x4& a1) {
    a0 = f32x4{0.f, 0.f, 0.f, 0.f};
    a1 = f32x4{0.f, 0.f, 0.f, 0.f};
    if (XBF16) {
      const unsigned short* aptr = xb + (((long)(t * B_ + b)) << 10) + lg * 8;
      #pragma unroll
      for (int it = 0; it < 32; ++it) {
        short8b a  = *reinterpret_cast<const short8b*>(aptr + it * 32);
        short8b bb = *reinterpret_cast<const short8b*>(WlB + colbase + ((it * 64 + lg * 16) ^ swz));
        if (it & 1) a1 = __builtin_amdgcn_mfma_f32_16x16x32_bf16(a, bb, a1, 0, 0, 0);
        else        a0 = __builtin_amdgcn_mfma_f32_16x16x32_bf16(a, bb, a0, 0, 0, 0);
      }
    } else {
      const float* aptr = xf + ((long)b * T_ + t) * I_ + lg * 8;
      #pragma unroll
      for (int it = 0; it < 32; ++it) {
        float4 v0 = *reinterpret_cast<const float4*>(aptr + it * 32);
        float4 v1 = *reinterpret_cast<const float4*>(aptr + it * 32 + 4);
        union { __hip_bfloat162 h2[4]; short8b v; } cv;
        cv.h2[0] = __float22bfloat162_rn(float2{v0.x, v0.y});
        cv.h2[1] = __float22bfloat162_rn(float2{v0.z, v0.w});
        cv.h2[2] = __float22bfloat162_rn(float2{v1.x, v1.y});
        cv.h2[3] = __float22bfloat162_rn(float2{v1.z, v1.w});
        short8b bb = *reinterpret_cast<const short8b*>(WlB + colbase + ((it * 64 + lg * 16) ^ swz));
        if (it & 1) a1 = __builtin_amdgcn_mfma_f32_16x16x32_bf16(cv.v, bb, a1, 0, 0, 0);
        else        a0 = __builtin_amdgcn_mfma_f32_16x16x32_bf16(cv.v, bb, a0, 0, 0, 0);
      }
    }
  };

  f32x4 xa0, xa1;
  xpart(0, xa0, xa1);

  for (int t = 0; t < T_; ++t) {
    f32x4 a0 = xa0, a1 = xa1;

    if (t > 0) {
      // ---- wave m polls ONLY its own chain's 256 flags (2x8B/lane) ----
      {
        const unsigned exp32 = MAGIC | (unsigned)(t - 1);
        const unsigned long long pat =
            ((unsigned long long)exp32 << 32) | (unsigned long long)exp32;
        const unsigned long long* fb = reinterpret_cast<const unsigned long long*>(
            flags + (long)(t - 1) * 512 + m * 256) + lane * 2;
        while (true) {
          unsigned long long f0 = ld64sys(fb);
          unsigned long long f1 = ld64sys(fb + 1);
          if (__all((f0 == pat) & (f1 == pat))) break;
        }
      }
      asm volatile("" ::: "memory");   // no cached h loads hoisted above the poll

      // ---- h-part GEMM: plain cached 8B loads from packed chunks ----
      const char* hb = hseqp + ((long)(t - 1) << 16) + m * 128 + lr * 8 + lg * 512;
      unsigned long long u0[8][2], u1[8][2];
      auto issue = [&](int g, unsigned long long (&u)[8][2]) {
        #pragma unroll
        for (int f = 0; f < 8; ++f) {
          const char* p = hb + ((g * 8 + f) * 8) * 256;   // chunk j = it*8 + lg*2
          u[f][0] = *reinterpret_cast<const unsigned long long*>(p);
          u[f][1] = *reinterpret_cast<const unsigned long long*>(p + 256);
        }
      };
      auto domfma = [&](int g, unsigned long long (&u)[8][2]) {
        #pragma unroll
        for (int f = 0; f < 8; ++f) {
          const int it = g * 8 + f;
          union { unsigned long long q[2]; short8b v; } cv;
          cv.q[0] = u[f][0]; cv.q[1] = u[f][1];
          short8b bb = *reinterpret_cast<const short8b*>(
              WlB + colbase + ((2048 + it * 64 + lg * 16) ^ swz));
          if (it & 1) a1 = __builtin_amdgcn_mfma_f32_16x16x32_bf16(cv.v, bb, a1, 0, 0, 0);
          else        a0 = __builtin_amdgcn_mfma_f32_16x16x32_bf16(cv.v, bb, a0, 0, 0, 0);
        }
      };
      issue(0, u0);
      issue(1, u1);
      domfma(0, u0); issue(2, u0);
      domfma(1, u1); issue(3, u1);
      domfma(2, u0);
      domfma(3, u1);
    }

    f32x4 acc = a0 + a1;

    // ---- gates: D[row=lg*4+r][col=lr]; lane wants cols g*4+cj ----
    float gate[4][4];
    #pragma unroll
    for (int g = 0; g < 4; ++g) {
      const int src = lg * 16 + g * 4 + cj;
      #pragma unroll
      for (int r = 0; r < 4; ++r) gate[g][r] = __shfl(acc[r], src, 64);
    }

    float hv[4];
    #pragma unroll
    for (int r = 0; r < 4; ++r) {
      float fg = sig_(gate[0][r] + bias_f);
      float ig = sig_(gate[1][r] + bias_i);
      float og = sig_(gate[2][r] + bias_o);
      float gg = tanh_(gate[3][r] + bias_g);
      float c  = fg * creg[r] + ig * gg;
      creg[r]  = c;
      hv[r]    = og * tanh_(c);
    }

    if (t < T_ - 1) {
      // ---- publish chunk (1 coalesced 128B store/wave) ----
      const int src = ((lane >> 4) << 4) | (lane & 3);   // source lane for (row,col)
      float hr0 = __shfl(hv[0], src, 64);
      float hr1 = __shfl(hv[1], src, 64);
      float hr2 = __shfl(hv[2], src, 64);
      float hr3 = __shfl(hv[3], src, 64);
      const int rsel = (lane >> 2) & 3;
      float v = (rsel == 0) ? hr0 : (rsel == 1) ? hr1 : (rsel == 2) ? hr2 : hr3;
      unsigned short hs = f2bf(v);
      __hip_atomic_store(
          reinterpret_cast<unsigned short*>(hseqp + ((long)t << 16) + bid * 256 + m * 128 + lane * 2),
          hs, __ATOMIC_RELAXED, SC_SYS);

      // ---- ack covers ONLY the chunk store; flag goes up ASAP (r13 law) ----
      asm volatile("s_waitcnt vmcnt(0)" ::: "memory");   // chunk landed at MALL
      if (lane == 0)
        __hip_atomic_store(&flags[(long)t * 512 + m * 256 + bid], MAGIC | (unsigned)t,
                           __ATOMIC_RELAXED, SC_SYS);

      // ---- h/c output stores drain in the rendezvous shadow ----
      if ((lane & 12) == 0) {
        #pragma unroll
        for (int r = 0; r < 4; ++r) {
          const long oh = (long)(t * B_ + gb0 + r) * H_ + j0 + cj;
          out[HLAST + oh]       = hv[r];
          out[HLAST + TBH + oh] = creg[r];
        }
      }
    } else {
      if ((lane & 12) == 0) {
        #pragma unroll
        for (int r = 0; r < 4; ++r) {
          const int row  = gb0 + r;
          const int colj = j0 + cj;
          const long oh  = (long)(t * B_ + row) * H_ + colj;
          out[HLAST + oh]        = hv[r];
          out[HLAST + TBH + oh]  = creg[r];
          out[(long)row * H_ + colj] = hv[r];
        }
      }
    }

    if (t + 1 < T_) xpart(t + 1, xa0, xa1);
  }
}

// Fallback (ws too small): per-step kernel gathering raw f32 each step.
__global__ void lstm_step_fallback_kernel(int t,
    const float* __restrict__ xf,
    const float* __restrict__ Wf, const float* __restrict__ Wi,
    const float* __restrict__ Wo, const float* __restrict__ Wc,
    const float* __restrict__ bfp, const float* __restrict__ bip,
    const float* __restrict__ bop, const float* __restrict__ bcp,
    float* __restrict__ out, unsigned short* __restrict__ hbuf)
{
  const int tid  = threadIdx.x;
  const int bid  = blockIdx.x;
  const int lane = tid & 63;
  const int m    = tid >> 6;
  const int lr   = lane & 15;
  const int lg   = lane >> 4;
  const int b    = m * 16 + lr;
  const int cj   = lane & 3;
  const int j0   = bid * 4;
  const int gb0  = m * 16 + lg * 4;

  const unsigned short* hcur = hbuf + (t & 1) * BH;
  f32x4 a0 = {0.f, 0.f, 0.f, 0.f};
  f32x4 a1 = {0.f, 0.f, 0.f, 0.f};

  const int g    = lr >> 2;
  const int colg = j0 + (lr & 3);
  const float* Wg = (g == 0) ? Wf : (g == 1) ? Wi : (g == 2) ? Wo : Wc;
  const float* axf = xf + ((long)b * T_ + t) * I_ + lg * 8;
  const unsigned short* ah = hcur + (b << 10) + lg * 8;
  #pragma unroll 4
  for (int it = 0; it < 32; ++it) {
    const int k0 = it * 32 + lg * 8;
    short8b a, bb;
    #pragma unroll
    for (int e = 0; e < 8; ++e) {
      a[e]  = (short)f2bf(axf[it * 32 + e]);
      bb[e] = (short)f2bf(Wg[(size_t)(k0 + e) * H_ + colg]);
    }
    if (it & 1) a1 = __builtin_amdgcn_mfma_f32_16x16x32_bf16(a, bb, a1, 0, 0, 0);
    else        a0 = __builtin_amdgcn_mfma_f32_16x16x32_bf16(a, bb, a0, 0, 0, 0);
  }
  #pragma unroll 4
  for (int it = 0; it < 32; ++it) {
    const int k0 = 1024 + it * 32 + lg * 8;
    short8b a = *reinterpret_cast<const short8b*>(ah + it * 32);
    short8b bb;
    #pragma unroll
    for (int e = 0; e < 8; ++e)
      bb[e] = (short)f2bf(Wg[(size_t)(k0 + e) * H_ + colg]);
    if (it & 1) a1 = __builtin_amdgcn_mfma_f32_16x16x32_bf16(a, bb, a1, 0, 0, 0);
    else        a0 = __builtin_amdgcn_mfma_f32_16x16x32_bf16(a, bb, a0, 0, 0, 0);
  }
  f32x4 acc = a0 + a1;

  float gate[4][4];
  #pragma unroll
  for (int gg = 0; gg < 4; ++gg) {
    const int src = lg * 16 + gg * 4 + cj;
    #pragma unroll
    for (int r = 0; r < 4; ++r) gate[gg][r] = __shfl(acc[r], src, 64);
  }

  if ((lane & 12) == 0) {
    const int col = j0 + cj;
    const float bias_f = bfp[col];
    const float bias_i = bip[col];
    const float bias_o = bop[col];
    const float bias_g = bcp[col];
    #pragma unroll
    for (int r = 0; r < 4; ++r) {
      const int row = gb0 + r;
      float cp = (t == 0) ? 0.f
               : out[HLAST + TBH + (long)((t - 1) * B_ + row) * H_ + col];
      float fg = sig_(gate[0][r] + bias_f);
      float ig = sig_(gate[1][r] + bias_i);
      float og = sig_(gate[2][r] + bias_o);
      float gv = tanh_(gate[3][r] + bias_g);
      float c  = fg * cp + ig * gv;
      float hv = og * tanh_(c);
      const long oh = (long)(t * B_ + row) * H_ + col;
      out[HLAST + oh]       = hv;
      out[HLAST + TBH + oh] = c;
      hbuf[((t + 1) & 1) * BH + row * H_ + col] = f2bf(hv);
      if (t == T_ - 1) out[(long)row * H_ + col] = hv;
    }
  }
}

extern "C" void kernel_launch(void* const* d_in, const int* in_sizes, int n_in,
                              void* d_out, int out_size, void* d_ws, size_t ws_size,
                              hipStream_t stream) {
  const float* x   = (const float*)d_in[0];
  const float* Wf  = (const float*)d_in[1];
  const float* bf_ = (const float*)d_in[2];
  const float* Wi  = (const float*)d_in[3];
  const float* bi_ = (const float*)d_in[4];
  const float* Wo  = (const float*)d_in[5];
  const float* bo_ = (const float*)d_in[6];
  const float* Wc  = (const float*)d_in[7];
  const float* bc_ = (const float*)d_in[8];
  float* out = (float*)d_out;

  const size_t hseq_bytes  = (size_t)T_ * 65536;          // 32 MiB packed chunks
  const size_t flags_bytes = (size_t)T_ * 512 * 4;        // 1 MiB per-wave flags
  const size_t xb_bytes    = (size_t)T_ * B_ * I_ * 2;    // 32 MiB
  const bool has_hseq = ws_size >= hseq_bytes + flags_bytes;
  const bool has_xb   = ws_size >= hseq_bytes + flags_bytes + xb_bytes;

  if (has_hseq) {
    char* hseqp        = (char*)d_ws;
    unsigned* flags    = (unsigned*)((char*)d_ws + hseq_bytes);
    unsigned short* xb = (unsigned short*)((char*)d_ws + hseq_bytes + flags_bytes);

    // only flags need re-arming each call (graph-replay safe); hseqp content
    // is gated by flags so its initial bytes are irrelevant.
    (void)hipMemsetAsync(flags, 0, flags_bytes, stream);

    if (has_xb) {
      const int total_vec = T_ * B_ * I_ / 4;
      convert_x_kernel<<<dim3(total_vec / 256), dim3(256), 0, stream>>>(x, xb);
      lstm_kernel<true><<<dim3(NB), dim3(NTHR), 0, stream>>>(
          xb, x, Wf, Wi, Wo, Wc, bf_, bi_, bo_, bc_, out, hseqp, flags);
    } else {
      lstm_kernel<false><<<dim3(NB), dim3(NTHR), 0, stream>>>(
          xb, x, Wf, Wi, Wo, Wc, bf_, bi_, bo_, bc_, out, hseqp, flags);
    }
  } else {
    unsigned short* hbuf = (unsigned short*)d_ws;
    (void)hipMemsetAsync(hbuf, 0, (size_t)2 * BH * 2, stream);
    for (int t = 0; t < T_; ++t)
      lstm_step_fallback_kernel<<<dim3(NB), dim3(128), 0, stream>>>(
          t, x, Wf, Wi, Wo, Wc, bf_, bi_, bo_, bc_, out, hbuf);
  }
}

// Round 17
// 2898.704 us; speedup vs baseline: 2.1736x; 1.0073x over previous
//
#include <hip/hip_runtime.h>
#include <hip/hip_bf16.h>

typedef __attribute__((ext_vector_type(8))) short short8b;
typedef __attribute__((ext_vector_type(4))) float f32x4;

#define B_   32
#define T_   512
#define I_   1024
#define H_   1024
#define K_   2048          // I + H
#define NB   256           // blocks, each owns 4 H-cols (16 gate cols); 1 per CU
#define NTHR 128           // 2 waves: wave m handles batch rows m*16..m*16+15
#define BH   (B_ * H_)
#define HLAST (B_ * H_)
#define TBH ((long)T_ * B_ * H_)
#define SC_SYS __HIP_MEMORY_SCOPE_SYSTEM
#define MAGIC 0x5AB00000u   // flag = MAGIC|t: != 0 (memset) and != 0xAAAAAAAA (poison)

__device__ __forceinline__ unsigned short f2bf(float f) {
  union { float f; unsigned u; } c; c.f = f;
  unsigned r = (c.u + 0x7FFFu + ((c.u >> 16) & 1u)) >> 16;  // RNE
  return (unsigned short)r;
}

__device__ __forceinline__ float sig_(float x)  { return 1.0f / (1.0f + __expf(-x)); }
__device__ __forceinline__ float tanh_(float x) { return 1.0f - 2.0f / (__expf(2.0f * x) + 1.0f); }

__device__ __forceinline__ unsigned long long ld64sys(const void* p) {
  return __hip_atomic_load((const unsigned long long*)p, __ATOMIC_RELAXED, SC_SYS);
}

// x [B][T][I] f32  ->  xb [T][B][I] bf16 (step-t slab contiguous)
__global__ void convert_x_kernel(const float* __restrict__ x, unsigned short* __restrict__ xb) {
  long vid = (long)blockIdx.x * blockDim.x + threadIdx.x;
  long o = vid * 4;
  if (o >= (long)T_ * B_ * I_) return;
  int i  = (int)(o & (I_ - 1));
  long bt = o >> 10;
  int b  = (int)(bt & (B_ - 1));
  int t  = (int)(bt >> 5);
  float4 v = *reinterpret_cast<const float4*>(x + (((long)b * T_ + t) << 10) + i);
  ushort4 pk;
  pk.x = f2bf(v.x); pk.y = f2bf(v.y); pk.z = f2bf(v.z); pk.w = f2bf(v.w);
  *reinterpret_cast<ushort4*>(xb + o) = pk;
}

// Persistent LSTM, plain launch (256 x 128, 64 KiB LDS -> 1 block/CU).
// r16 structure with ONE change: loop-tail order is flag -> xpart -> outs
// (was flag -> outs -> xpart). vmcnt is a SHARED in-order counter for loads
// AND stores, so xpart's load-waits previously folded in the 8 scattered f32
// out-stores' write-allocate acks (cold-line HBM fetches) -- putting an HBM
// round-trip on the xpart path every step. Now the outs drain during the
// poll spin, where their latency folds into the detect window.
template <bool XBF16>
__global__ __launch_bounds__(NTHR, 1)
void lstm_kernel(const unsigned short* __restrict__ xb, const float* __restrict__ xf,
                 const float* __restrict__ Wf, const float* __restrict__ Wi,
                 const float* __restrict__ Wo, const float* __restrict__ Wc,
                 const float* __restrict__ bfp, const float* __restrict__ bip,
                 const float* __restrict__ bop, const float* __restrict__ bcp,
                 float* __restrict__ out, char* __restrict__ hseqp,
                 unsigned* __restrict__ flags)
{
  __shared__ unsigned short Wl[16 * 2048];  // 64 KiB weight stripe (bf16, swizzled)
  const int tid = threadIdx.x;
  const int bid = blockIdx.x;
  const int j0  = bid * 4;

  {
    const float* Wg[4] = {Wf, Wi, Wo, Wc};
    for (int g = 0; g < 4; ++g) {
      const float* Wp = Wg[g] + j0;
      for (int k = tid; k < K_; k += NTHR) {
        float4 w = *reinterpret_cast<const float4*>(Wp + (long)k * H_);
        float wv[4] = {w.x, w.y, w.z, w.w};
        #pragma unroll
        for (int cj = 0; cj < 4; ++cj) {
          int n = g * 4 + cj;
          int byteoff = n * 4096 + ((2 * k) ^ ((n & 7) << 4));
          *reinterpret_cast<unsigned short*>(reinterpret_cast<char*>(Wl) + byteoff) = f2bf(wv[cj]);
        }
      }
    }
  }
  __syncthreads();

  // Purge pre-kernel L1/L2 residue once; after this, hseqp lines enter caches
  // only via our own post-flag reads.
  __builtin_amdgcn_fence(__ATOMIC_ACQUIRE, "agent");

  const int lane = tid & 63;
  const int m    = tid >> 6;
  const int lr   = lane & 15;
  const int lg   = lane >> 4;
  const int b    = m * 16 + lr;     // batch row fed into A-fragment
  const int cj   = lane & 3;        // H-column (within block) this lane gates
  const int gb0  = m * 16 + lg * 4; // first batch row this lane gates

  const float bias_f = bfp[j0 + cj];
  const float bias_i = bip[j0 + cj];
  const float bias_o = bop[j0 + cj];
  const float bias_g = bcp[j0 + cj];

  float creg[4] = {0.f, 0.f, 0.f, 0.f};  // c state in registers for all T steps

  const char* WlB   = reinterpret_cast<const char*>(Wl);
  const int colbase = lr * 4096;
  const int swz     = (lr & 7) << 4;

  // x-part GEMM for step t (runs right after the flag; no store-drain ahead)
  auto xpart = [&](int t, f32x4& a0, f32x4& a1) {
    a0 = f32x4{0.f, 0.f, 0.f, 0.f};
    a1 = f32x4{0.f, 0.f, 0.f, 0.f};
    if (XBF16) {
      const unsigned short* aptr = xb + (((long)(t * B_ + b)) << 10) + lg * 8;
      #pragma unroll
      for (int it = 0; it < 32; ++it) {
        short8b a  = *reinterpret_cast<const short8b*>(aptr + it * 32);
        short8b bb = *reinterpret_cast<const short8b*>(WlB + colbase + ((it * 64 + lg * 16) ^ swz));
        if (it & 1) a1 = __builtin_amdgcn_mfma_f32_16x16x32_bf16(a, bb, a1, 0, 0, 0);
        else        a0 = __builtin_amdgcn_mfma_f32_16x16x32_bf16(a, bb, a0, 0, 0, 0);
      }
    } else {
      const float* aptr = xf + ((long)b * T_ + t) * I_ + lg * 8;
      #pragma unroll
      for (int it = 0; it < 32; ++it) {
        float4 v0 = *reinterpret_cast<const float4*>(aptr + it * 32);
        float4 v1 = *reinterpret_cast<const float4*>(aptr + it * 32 + 4);
        union { __hip_bfloat162 h2[4]; short8b v; } cv;
        cv.h2[0] = __float22bfloat162_rn(float2{v0.x, v0.y});
        cv.h2[1] = __float22bfloat162_rn(float2{v0.z, v0.w});
        cv.h2[2] = __float22bfloat162_rn(float2{v1.x, v1.y});
        cv.h2[3] = __float22bfloat162_rn(float2{v1.z, v1.w});
        short8b bb = *reinterpret_cast<const short8b*>(WlB + colbase + ((it * 64 + lg * 16) ^ swz));
        if (it & 1) a1 = __builtin_amdgcn_mfma_f32_16x16x32_bf16(cv.v, bb, a1, 0, 0, 0);
        else        a0 = __builtin_amdgcn_mfma_f32_16x16x32_bf16(cv.v, bb, a0, 0, 0, 0);
      }
    }
  };

  f32x4 xa0, xa1;
  xpart(0, xa0, xa1);

  for (int t = 0; t < T_; ++t) {
    f32x4 a0 = xa0, a1 = xa1;

    if (t > 0) {
      // ---- wave m polls ONLY its own chain's 256 flags (2x8B/lane) ----
      // (the previous step's out-stores drain inside this spin window)
      {
        const unsigned exp32 = MAGIC | (unsigned)(t - 1);
        const unsigned long long pat =
            ((unsigned long long)exp32 << 32) | (unsigned long long)exp32;
        const unsigned long long* fb = reinterpret_cast<const unsigned long long*>(
            flags + (long)(t - 1) * 512 + m * 256) + lane * 2;
        while (true) {
          unsigned long long f0 = ld64sys(fb);
          unsigned long long f1 = ld64sys(fb + 1);
          if (__all((f0 == pat) & (f1 == pat))) break;
        }
      }
      asm volatile("" ::: "memory");   // no cached h loads hoisted above the poll

      // ---- h-part GEMM: plain cached 8B loads from packed chunks ----
      const char* hb = hseqp + ((long)(t - 1) << 16) + m * 128 + lr * 8 + lg * 512;
      unsigned long long u0[8][2], u1[8][2];
      auto issue = [&](int g, unsigned long long (&u)[8][2]) {
        #pragma unroll
        for (int f = 0; f < 8; ++f) {
          const char* p = hb + ((g * 8 + f) * 8) * 256;   // chunk j = it*8 + lg*2
          u[f][0] = *reinterpret_cast<const unsigned long long*>(p);
          u[f][1] = *reinterpret_cast<const unsigned long long*>(p + 256);
        }
      };
      auto domfma = [&](int g, unsigned long long (&u)[8][2]) {
        #pragma unroll
        for (int f = 0; f < 8; ++f) {
          const int it = g * 8 + f;
          union { unsigned long long q[2]; short8b v; } cv;
          cv.q[0] = u[f][0]; cv.q[1] = u[f][1];
          short8b bb = *reinterpret_cast<const short8b*>(
              WlB + colbase + ((2048 + it * 64 + lg * 16) ^ swz));
          if (it & 1) a1 = __builtin_amdgcn_mfma_f32_16x16x32_bf16(cv.v, bb, a1, 0, 0, 0);
          else        a0 = __builtin_amdgcn_mfma_f32_16x16x32_bf16(cv.v, bb, a0, 0, 0, 0);
        }
      };
      issue(0, u0);
      issue(1, u1);
      domfma(0, u0); issue(2, u0);
      domfma(1, u1); issue(3, u1);
      domfma(2, u0);
      domfma(3, u1);
    }

    f32x4 acc = a0 + a1;

    // ---- gates: D[row=lg*4+r][col=lr]; lane wants cols g*4+cj ----
    float gate[4][4];
    #pragma unroll
    for (int g = 0; g < 4; ++g) {
      const int src = lg * 16 + g * 4 + cj;
      #pragma unroll
      for (int r = 0; r < 4; ++r) gate[g][r] = __shfl(acc[r], src, 64);
    }

    float hv[4];
    #pragma unroll
    for (int r = 0; r < 4; ++r) {
      float fg = sig_(gate[0][r] + bias_f);
      float ig = sig_(gate[1][r] + bias_i);
      float og = sig_(gate[2][r] + bias_o);
      float gg = tanh_(gate[3][r] + bias_g);
      float c  = fg * creg[r] + ig * gg;
      creg[r]  = c;
      hv[r]    = og * tanh_(c);
    }

    if (t < T_ - 1) {
      // ---- publish chunk (1 coalesced 128B store/wave) ----
      const int src = ((lane >> 4) << 4) | (lane & 3);   // source lane for (row,col)
      float hr0 = __shfl(hv[0], src, 64);
      float hr1 = __shfl(hv[1], src, 64);
      float hr2 = __shfl(hv[2], src, 64);
      float hr3 = __shfl(hv[3], src, 64);
      const int rsel = (lane >> 2) & 3;
      float v = (rsel == 0) ? hr0 : (rsel == 1) ? hr1 : (rsel == 2) ? hr2 : hr3;
      unsigned short hs = f2bf(v);
      __hip_atomic_store(
          reinterpret_cast<unsigned short*>(hseqp + ((long)t << 16) + bid * 256 + m * 128 + lane * 2),
          hs, __ATOMIC_RELAXED, SC_SYS);

      // ---- ack covers ONLY the chunk store; flag goes up ASAP (r13 law) ----
      asm volatile("s_waitcnt vmcnt(0)" ::: "memory");   // chunk landed at MALL
      if (lane == 0)
        __hip_atomic_store(&flags[(long)t * 512 + m * 256 + bid], MAGIC | (unsigned)t,
                           __ATOMIC_RELAXED, SC_SYS);

      // ---- next-step x-GEMM FIRST (no store-drain ahead of its loads) ----
      xpart(t + 1, xa0, xa1);

      // ---- h/c output stores LAST: drain during the upcoming poll spin ----
      if ((lane & 12) == 0) {
        #pragma unroll
        for (int r = 0; r < 4; ++r) {
          const long oh = (long)(t * B_ + gb0 + r) * H_ + j0 + cj;
          out[HLAST + oh]       = hv[r];
          out[HLAST + TBH + oh] = creg[r];
        }
      }
    } else {
      if ((lane & 12) == 0) {
        #pragma unroll
        for (int r = 0; r < 4; ++r) {
          const int row  = gb0 + r;
          const int colj = j0 + cj;
          const long oh  = (long)(t * B_ + row) * H_ + colj;
          out[HLAST + oh]        = hv[r];
          out[HLAST + TBH + oh]  = creg[r];
          out[(long)row * H_ + colj] = hv[r];
        }
      }
    }
  }
}

// Fallback (ws too small): per-step kernel gathering raw f32 each step.
__global__ void lstm_step_fallback_kernel(int t,
    const float* __restrict__ xf,
    const float* __restrict__ Wf, const float* __restrict__ Wi,
    const float* __restrict__ Wo, const float* __restrict__ Wc,
    const float* __restrict__ bfp, const float* __restrict__ bip,
    const float* __restrict__ bop, const float* __restrict__ bcp,
    float* __restrict__ out, unsigned short* __restrict__ hbuf)
{
  const int tid  = threadIdx.x;
  const int bid  = blockIdx.x;
  const int lane = tid & 63;
  const int m    = tid >> 6;
  const int lr   = lane & 15;
  const int lg   = lane >> 4;
  const int b    = m * 16 + lr;
  const int cj   = lane & 3;
  const int j0   = bid * 4;
  const int gb0  = m * 16 + lg * 4;

  const unsigned short* hcur = hbuf + (t & 1) * BH;
  f32x4 a0 = {0.f, 0.f, 0.f, 0.f};
  f32x4 a1 = {0.f, 0.f, 0.f, 0.f};

  const int g    = lr >> 2;
  const int colg = j0 + (lr & 3);
  const float* Wg = (g == 0) ? Wf : (g == 1) ? Wi : (g == 2) ? Wo : Wc;
  const float* axf = xf + ((long)b * T_ + t) * I_ + lg * 8;
  const unsigned short* ah = hcur + (b << 10) + lg * 8;
  #pragma unroll 4
  for (int it = 0; it < 32; ++it) {
    const int k0 = it * 32 + lg * 8;
    short8b a, bb;
    #pragma unroll
    for (int e = 0; e < 8; ++e) {
      a[e]  = (short)f2bf(axf[it * 32 + e]);
      bb[e] = (short)f2bf(Wg[(size_t)(k0 + e) * H_ + colg]);
    }
    if (it & 1) a1 = __builtin_amdgcn_mfma_f32_16x16x32_bf16(a, bb, a1, 0, 0, 0);
    else        a0 = __builtin_amdgcn_mfma_f32_16x16x32_bf16(a, bb, a0, 0, 0, 0);
  }
  #pragma unroll 4
  for (int it = 0; it < 32; ++it) {
    const int k0 = 1024 + it * 32 + lg * 8;
    short8b a = *reinterpret_cast<const short8b*>(ah + it * 32);
    short8b bb;
    #pragma unroll
    for (int e = 0; e < 8; ++e)
      bb[e] = (short)f2bf(Wg[(size_t)(k0 + e) * H_ + colg]);
    if (it & 1) a1 = __builtin_amdgcn_mfma_f32_16x16x32_bf16(a, bb, a1, 0, 0, 0);
    else        a0 = __builtin_amdgcn_mfma_f32_16x16x32_bf16(a, bb, a0, 0, 0, 0);
  }
  f32x4 acc = a0 + a1;

  float gate[4][4];
  #pragma unroll
  for (int gg = 0; gg < 4; ++gg) {
    const int src = lg * 16 + gg * 4 + cj;
    #pragma unroll
    for (int r = 0; r < 4; ++r) gate[gg][r] = __shfl(acc[r], src, 64);
  }

  if ((lane & 12) == 0) {
    const int col = j0 + cj;
    const float bias_f = bfp[col];
    const float bias_i = bip[col];
    const float bias_o = bop[col];
    const float bias_g = bcp[col];
    #pragma unroll
    for (int r = 0; r < 4; ++r) {
      const int row = gb0 + r;
      float cp = (t == 0) ? 0.f
               : out[HLAST + TBH + (long)((t - 1) * B_ + row) * H_ + col];
      float fg = sig_(gate[0][r] + bias_f);
      float ig = sig_(gate[1][r] + bias_i);
      float og = sig_(gate[2][r] + bias_o);
      float gv = tanh_(gate[3][r] + bias_g);
      float c  = fg * cp + ig * gv;
      float hv = og * tanh_(c);
      const long oh = (long)(t * B_ + row) * H_ + col;
      out[HLAST + oh]       = hv;
      out[HLAST + TBH + oh] = c;
      hbuf[((t + 1) & 1) * BH + row * H_ + col] = f2bf(hv);
      if (t == T_ - 1) out[(long)row * H_ + col] = hv;
    }
  }
}

extern "C" void kernel_launch(void* const* d_in, const int* in_sizes, int n_in,
                              void* d_out, int out_size, void* d_ws, size_t ws_size,
                              hipStream_t stream) {
  const float* x   = (const float*)d_in[0];
  const float* Wf  = (const float*)d_in[1];
  const float* bf_ = (const float*)d_in[2];
  const float* Wi  = (const float*)d_in[3];
  const float* bi_ = (const float*)d_in[4];
  const float* Wo  = (const float*)d_in[5];
  const float* bo_ = (const float*)d_in[6];
  const float* Wc  = (const float*)d_in[7];
  const float* bc_ = (const float*)d_in[8];
  float* out = (float*)d_out;

  const size_t hseq_bytes  = (size_t)T_ * 65536;          // 32 MiB packed chunks
  const size_t flags_bytes = (size_t)T_ * 512 * 4;        // 1 MiB per-wave flags
  const size_t xb_bytes    = (size_t)T_ * B_ * I_ * 2;    // 32 MiB
  const bool has_hseq = ws_size >= hseq_bytes + flags_bytes;
  const bool has_xb   = ws_size >= hseq_bytes + flags_bytes + xb_bytes;

  if (has_hseq) {
    char* hseqp        = (char*)d_ws;
    unsigned* flags    = (unsigned*)((char*)d_ws + hseq_bytes);
    unsigned short* xb = (unsigned short*)((char*)d_ws + hseq_bytes + flags_bytes);

    // only flags need re-arming each call (graph-replay safe); hseqp content
    // is gated by flags so its initial bytes are irrelevant.
    (void)hipMemsetAsync(flags, 0, flags_bytes, stream);

    if (has_xb) {
      const int total_vec = T_ * B_ * I_ / 4;
      convert_x_kernel<<<dim3(total_vec / 256), dim3(256), 0, stream>>>(x, xb);
      lstm_kernel<true><<<dim3(NB), dim3(NTHR), 0, stream>>>(
          xb, x, Wf, Wi, Wo, Wc, bf_, bi_, bo_, bc_, out, hseqp, flags);
    } else {
      lstm_kernel<false><<<dim3(NB), dim3(NTHR), 0, stream>>>(
          xb, x, Wf, Wi, Wo, Wc, bf_, bi_, bo_, bc_, out, hseqp, flags);
    }
  } else {
    unsigned short* hbuf = (unsigned short*)d_ws;
    (void)hipMemsetAsync(hbuf, 0, (size_t)2 * BH * 2, stream);
    for (int t = 0; t < T_; ++t)
      lstm_step_fallback_kernel<<<dim3(NB), dim3(128), 0, stream>>>(
          t, x, Wf, Wi, Wo, Wc, bf_, bi_, bo_, bc_, out, hbuf);
  }
}

// Round 18
// 2883.496 us; speedup vs baseline: 2.1850x; 1.0053x over previous
//
#include <hip/hip_runtime.h>
#include <hip/hip_bf16.h>

typedef __attribute__((ext_vector_type(8))) short short8b;
typedef __attribute__((ext_vector_type(4))) float f32x4;

#define B_   32
#define T_   512
#define I_   1024
#define H_   1024
#define K_   2048          // I + H
#define NB   256           // blocks, each owns 4 H-cols (16 gate cols); 1 per CU
#define NTHR 128           // 2 waves: wave m handles batch rows m*16..m*16+15
#define BH   (B_ * H_)
#define HLAST (B_ * H_)
#define TBH ((long)T_ * B_ * H_)
#define SC_SYS __HIP_MEMORY_SCOPE_SYSTEM
#define MAGIC 0x5AB00000u   // flag = MAGIC|t: != 0 (memset) and != 0xAAAAAAAA (poison)

__device__ __forceinline__ unsigned short f2bf(float f) {
  union { float f; unsigned u; } c; c.f = f;
  unsigned r = (c.u + 0x7FFFu + ((c.u >> 16) & 1u)) >> 16;  // RNE
  return (unsigned short)r;
}

__device__ __forceinline__ float sig_(float x)  { return 1.0f / (1.0f + __expf(-x)); }
__device__ __forceinline__ float tanh_(float x) { return 1.0f - 2.0f / (__expf(2.0f * x) + 1.0f); }

__device__ __forceinline__ unsigned long long ld64sys(const void* p) {
  return __hip_atomic_load((const unsigned long long*)p, __ATOMIC_RELAXED, SC_SYS);
}

// x [B][T][I] f32  ->  xb [T][B][I] bf16 (step-t slab contiguous)
__global__ void convert_x_kernel(const float* __restrict__ x, unsigned short* __restrict__ xb) {
  long vid = (long)blockIdx.x * blockDim.x + threadIdx.x;
  long o = vid * 4;
  if (o >= (long)T_ * B_ * I_) return;
  int i  = (int)(o & (I_ - 1));
  long bt = o >> 10;
  int b  = (int)(bt & (B_ - 1));
  int t  = (int)(bt >> 5);
  float4 v = *reinterpret_cast<const float4*>(x + (((long)b * T_ + t) << 10) + i);
  ushort4 pk;
  pk.x = f2bf(v.x); pk.y = f2bf(v.y); pk.z = f2bf(v.z); pk.w = f2bf(v.w);
  *reinterpret_cast<ushort4*>(xb + o) = pk;
}

// Persistent LSTM, plain launch (256 x 128, 64 KiB LDS -> 1 block/CU).
// r17 structure with ONE change: all h_states/c_states output stores are
// NON-TEMPORAL (nt flag, no L3 allocation). The 256 MB f32 output stream was
// cycling the entire 256 MB Infinity Cache once per call, evicting the
// protocol working set (flags, hseqp chunks, xb) and pushing every
// rendezvous hop from MALL-class to HBM-class latency. NT stores keep the
// ~33 MB protocol set L3-resident; output bytes still reach HBM unchanged.
template <bool XBF16>
__global__ __launch_bounds__(NTHR, 1)
void lstm_kernel(const unsigned short* __restrict__ xb, const float* __restrict__ xf,
                 const float* __restrict__ Wf, const float* __restrict__ Wi,
                 const float* __restrict__ Wo, const float* __restrict__ Wc,
                 const float* __restrict__ bfp, const float* __restrict__ bip,
                 const float* __restrict__ bop, const float* __restrict__ bcp,
                 float* __restrict__ out, char* __restrict__ hseqp,
                 unsigned* __restrict__ flags)
{
  __shared__ unsigned short Wl[16 * 2048];  // 64 KiB weight stripe (bf16, swizzled)
  const int tid = threadIdx.x;
  const int bid = blockIdx.x;
  const int j0  = bid * 4;

  {
    const float* Wg[4] = {Wf, Wi, Wo, Wc};
    for (int g = 0; g < 4; ++g) {
      const float* Wp = Wg[g] + j0;
      for (int k = tid; k < K_; k += NTHR) {
        float4 w = *reinterpret_cast<const float4*>(Wp + (long)k * H_);
        float wv[4] = {w.x, w.y, w.z, w.w};
        #pragma unroll
        for (int cj = 0; cj < 4; ++cj) {
          int n = g * 4 + cj;
          int byteoff = n * 4096 + ((2 * k) ^ ((n & 7) << 4));
          *reinterpret_cast<unsigned short*>(reinterpret_cast<char*>(Wl) + byteoff) = f2bf(wv[cj]);
        }
      }
    }
  }
  __syncthreads();

  // Purge pre-kernel L1/L2 residue once; after this, hseqp lines enter caches
  // only via our own post-flag reads.
  __builtin_amdgcn_fence(__ATOMIC_ACQUIRE, "agent");

  const int lane = tid & 63;
  const int m    = tid >> 6;
  const int lr   = lane & 15;
  const int lg   = lane >> 4;
  const int b    = m * 16 + lr;     // batch row fed into A-fragment
  const int cj   = lane & 3;        // H-column (within block) this lane gates
  const int gb0  = m * 16 + lg * 4; // first batch row this lane gates

  const float bias_f = bfp[j0 + cj];
  const float bias_i = bip[j0 + cj];
  const float bias_o = bop[j0 + cj];
  const float bias_g = bcp[j0 + cj];

  float creg[4] = {0.f, 0.f, 0.f, 0.f};  // c state in registers for all T steps

  const char* WlB   = reinterpret_cast<const char*>(Wl);
  const int colbase = lr * 4096;
  const int swz     = (lr & 7) << 4;

  // x-part GEMM for step t (runs right after the flag; no store-drain ahead)
  auto xpart = [&](int t, f32x4& a0, f32x4& a1) {
    a0 = f32x4{0.f, 0.f, 0.f, 0.f};
    a1 = f32x4{0.f, 0.f, 0.f, 0.f};
    if (XBF16) {
      const unsigned short* aptr = xb + (((long)(t * B_ + b)) << 10) + lg * 8;
      #pragma unroll
      for (int it = 0; it < 32; ++it) {
        short8b a  = *reinterpret_cast<const short8b*>(aptr + it * 32);
        short8b bb = *reinterpret_cast<const short8b*>(WlB + colbase + ((it * 64 + lg * 16) ^ swz));
        if (it & 1) a1 = __builtin_amdgcn_mfma_f32_16x16x32_bf16(a, bb, a1, 0, 0, 0);
        else        a0 = __builtin_amdgcn_mfma_f32_16x16x32_bf16(a, bb, a0, 0, 0, 0);
      }
    } else {
      const float* aptr = xf + ((long)b * T_ + t) * I_ + lg * 8;
      #pragma unroll
      for (int it = 0; it < 32; ++it) {
        float4 v0 = *reinterpret_cast<const float4*>(aptr + it * 32);
        float4 v1 = *reinterpret_cast<const float4*>(aptr + it * 32 + 4);
        union { __hip_bfloat162 h2[4]; short8b v; } cv;
        cv.h2[0] = __float22bfloat162_rn(float2{v0.x, v0.y});
        cv.h2[1] = __float22bfloat162_rn(float2{v0.z, v0.w});
        cv.h2[2] = __float22bfloat162_rn(float2{v1.x, v1.y});
        cv.h2[3] = __float22bfloat162_rn(float2{v1.z, v1.w});
        short8b bb = *reinterpret_cast<const short8b*>(WlB + colbase + ((it * 64 + lg * 16) ^ swz));
        if (it & 1) a1 = __builtin_amdgcn_mfma_f32_16x16x32_bf16(cv.v, bb, a1, 0, 0, 0);
        else        a0 = __builtin_amdgcn_mfma_f32_16x16x32_bf16(cv.v, bb, a0, 0, 0, 0);
      }
    }
  };

  f32x4 xa0, xa1;
  xpart(0, xa0, xa1);

  for (int t = 0; t < T_; ++t) {
    f32x4 a0 = xa0, a1 = xa1;

    if (t > 0) {
      // ---- wave m polls ONLY its own chain's 256 flags (2x8B/lane) ----
      // (the previous step's out-stores drain inside this spin window)
      {
        const unsigned exp32 = MAGIC | (unsigned)(t - 1);
        const unsigned long long pat =
            ((unsigned long long)exp32 << 32) | (unsigned long long)exp32;
        const unsigned long long* fb = reinterpret_cast<const unsigned long long*>(
            flags + (long)(t - 1) * 512 + m * 256) + lane * 2;
        while (true) {
          unsigned long long f0 = ld64sys(fb);
          unsigned long long f1 = ld64sys(fb + 1);
          if (__all((f0 == pat) & (f1 == pat))) break;
        }
      }
      asm volatile("" ::: "memory");   // no cached h loads hoisted above the poll

      // ---- h-part GEMM: plain cached 8B loads from packed chunks ----
      const char* hb = hseqp + ((long)(t - 1) << 16) + m * 128 + lr * 8 + lg * 512;
      unsigned long long u0[8][2], u1[8][2];
      auto issue = [&](int g, unsigned long long (&u)[8][2]) {
        #pragma unroll
        for (int f = 0; f < 8; ++f) {
          const char* p = hb + ((g * 8 + f) * 8) * 256;   // chunk j = it*8 + lg*2
          u[f][0] = *reinterpret_cast<const unsigned long long*>(p);
          u[f][1] = *reinterpret_cast<const unsigned long long*>(p + 256);
        }
      };
      auto domfma = [&](int g, unsigned long long (&u)[8][2]) {
        #pragma unroll
        for (int f = 0; f < 8; ++f) {
          const int it = g * 8 + f;
          union { unsigned long long q[2]; short8b v; } cv;
          cv.q[0] = u[f][0]; cv.q[1] = u[f][1];
          short8b bb = *reinterpret_cast<const short8b*>(
              WlB + colbase + ((2048 + it * 64 + lg * 16) ^ swz));
          if (it & 1) a1 = __builtin_amdgcn_mfma_f32_16x16x32_bf16(cv.v, bb, a1, 0, 0, 0);
          else        a0 = __builtin_amdgcn_mfma_f32_16x16x32_bf16(cv.v, bb, a0, 0, 0, 0);
        }
      };
      issue(0, u0);
      issue(1, u1);
      domfma(0, u0); issue(2, u0);
      domfma(1, u1); issue(3, u1);
      domfma(2, u0);
      domfma(3, u1);
    }

    f32x4 acc = a0 + a1;

    // ---- gates: D[row=lg*4+r][col=lr]; lane wants cols g*4+cj ----
    float gate[4][4];
    #pragma unroll
    for (int g = 0; g < 4; ++g) {
      const int src = lg * 16 + g * 4 + cj;
      #pragma unroll
      for (int r = 0; r < 4; ++r) gate[g][r] = __shfl(acc[r], src, 64);
    }

    float hv[4];
    #pragma unroll
    for (int r = 0; r < 4; ++r) {
      float fg = sig_(gate[0][r] + bias_f);
      float ig = sig_(gate[1][r] + bias_i);
      float og = sig_(gate[2][r] + bias_o);
      float gg = tanh_(gate[3][r] + bias_g);
      float c  = fg * creg[r] + ig * gg;
      creg[r]  = c;
      hv[r]    = og * tanh_(c);
    }

    if (t < T_ - 1) {
      // ---- publish chunk (1 coalesced 128B store/wave) ----
      const int src = ((lane >> 4) << 4) | (lane & 3);   // source lane for (row,col)
      float hr0 = __shfl(hv[0], src, 64);
      float hr1 = __shfl(hv[1], src, 64);
      float hr2 = __shfl(hv[2], src, 64);
      float hr3 = __shfl(hv[3], src, 64);
      const int rsel = (lane >> 2) & 3;
      float v = (rsel == 0) ? hr0 : (rsel == 1) ? hr1 : (rsel == 2) ? hr2 : hr3;
      unsigned short hs = f2bf(v);
      __hip_atomic_store(
          reinterpret_cast<unsigned short*>(hseqp + ((long)t << 16) + bid * 256 + m * 128 + lane * 2),
          hs, __ATOMIC_RELAXED, SC_SYS);

      // ---- ack covers ONLY the chunk store; flag goes up ASAP (r13 law) ----
      asm volatile("s_waitcnt vmcnt(0)" ::: "memory");   // chunk landed at MALL
      if (lane == 0)
        __hip_atomic_store(&flags[(long)t * 512 + m * 256 + bid], MAGIC | (unsigned)t,
                           __ATOMIC_RELAXED, SC_SYS);

      // ---- next-step x-GEMM FIRST (no store-drain ahead of its loads) ----
      xpart(t + 1, xa0, xa1);

      // ---- h/c output stores LAST, NON-TEMPORAL (no L3 allocation):
      //      the 256 MB output stream must not evict the protocol set.
      if ((lane & 12) == 0) {
        #pragma unroll
        for (int r = 0; r < 4; ++r) {
          const long oh = (long)(t * B_ + gb0 + r) * H_ + j0 + cj;
          __builtin_nontemporal_store(hv[r],    &out[HLAST + oh]);
          __builtin_nontemporal_store(creg[r],  &out[HLAST + TBH + oh]);
        }
      }
    } else {
      if ((lane & 12) == 0) {
        #pragma unroll
        for (int r = 0; r < 4; ++r) {
          const int row  = gb0 + r;
          const int colj = j0 + cj;
          const long oh  = (long)(t * B_ + row) * H_ + colj;
          __builtin_nontemporal_store(hv[r],   &out[HLAST + oh]);
          __builtin_nontemporal_store(creg[r], &out[HLAST + TBH + oh]);
          __builtin_nontemporal_store(hv[r],   &out[(long)row * H_ + colj]);
        }
      }
    }
  }
}

// Fallback (ws too small): per-step kernel gathering raw f32 each step.
__global__ void lstm_step_fallback_kernel(int t,
    const float* __restrict__ xf,
    const float* __restrict__ Wf, const float* __restrict__ Wi,
    const float* __restrict__ Wo, const float* __restrict__ Wc,
    const float* __restrict__ bfp, const float* __restrict__ bip,
    const float* __restrict__ bop, const float* __restrict__ bcp,
    float* __restrict__ out, unsigned short* __restrict__ hbuf)
{
  const int tid  = threadIdx.x;
  const int bid  = blockIdx.x;
  const int lane = tid & 63;
  const int m    = tid >> 6;
  const int lr   = lane & 15;
  const int lg   = lane >> 4;
  const int b    = m * 16 + lr;
  const int cj   = lane & 3;
  const int j0   = bid * 4;
  const int gb0  = m * 16 + lg * 4;

  const unsigned short* hcur = hbuf + (t & 1) * BH;
  f32x4 a0 = {0.f, 0.f, 0.f, 0.f};
  f32x4 a1 = {0.f, 0.f, 0.f, 0.f};

  const int g    = lr >> 2;
  const int colg = j0 + (lr & 3);
  const float* Wg = (g == 0) ? Wf : (g == 1) ? Wi : (g == 2) ? Wo : Wc;
  const float* axf = xf + ((long)b * T_ + t) * I_ + lg * 8;
  const unsigned short* ah = hcur + (b << 10) + lg * 8;
  #pragma unroll 4
  for (int it = 0; it < 32; ++it) {
    const int k0 = it * 32 + lg * 8;
    short8b a, bb;
    #pragma unroll
    for (int e = 0; e < 8; ++e) {
      a[e]  = (short)f2bf(axf[it * 32 + e]);
      bb[e] = (short)f2bf(Wg[(size_t)(k0 + e) * H_ + colg]);
    }
    if (it & 1) a1 = __builtin_amdgcn_mfma_f32_16x16x32_bf16(a, bb, a1, 0, 0, 0);
    else        a0 = __builtin_amdgcn_mfma_f32_16x16x32_bf16(a, bb, a0, 0, 0, 0);
  }
  #pragma unroll 4
  for (int it = 0; it < 32; ++it) {
    const int k0 = 1024 + it * 32 + lg * 8;
    short8b a = *reinterpret_cast<const short8b*>(ah + it * 32);
    short8b bb;
    #pragma unroll
    for (int e = 0; e < 8; ++e)
      bb[e] = (short)f2bf(Wg[(size_t)(k0 + e) * H_ + colg]);
    if (it & 1) a1 = __builtin_amdgcn_mfma_f32_16x16x32_bf16(a, bb, a1, 0, 0, 0);
    else        a0 = __builtin_amdgcn_mfma_f32_16x16x32_bf16(a, bb, a0, 0, 0, 0);
  }
  f32x4 acc = a0 + a1;

  float gate[4][4];
  #pragma unroll
  for (int gg = 0; gg < 4; ++gg) {
    const int src = lg * 16 + gg * 4 + cj;
    #pragma unroll
    for (int r = 0; r < 4; ++r) gate[gg][r] = __shfl(acc[r], src, 64);
  }

  if ((lane & 12) == 0) {
    const int col = j0 + cj;
    const float bias_f = bfp[col];
    const float bias_i = bip[col];
    const float bias_o = bop[col];
    const float bias_g = bcp[col];
    #pragma unroll
    for (int r = 0; r < 4; ++r) {
      const int row = gb0 + r;
      float cp = (t == 0) ? 0.f
               : out[HLAST + TBH + (long)((t - 1) * B_ + row) * H_ + col];
      float fg = sig_(gate[0][r] + bias_f);
      float ig = sig_(gate[1][r] + bias_i);
      float og = sig_(gate[2][r] + bias_o);
      float gv = tanh_(gate[3][r] + bias_g);
      float c  = fg * cp + ig * gv;
      float hv = og * tanh_(c);
      const long oh = (long)(t * B_ + row) * H_ + col;
      out[HLAST + oh]       = hv;
      out[HLAST + TBH + oh] = c;
      hbuf[((t + 1) & 1) * BH + row * H_ + col] = f2bf(hv);
      if (t == T_ - 1) out[(long)row * H_ + col] = hv;
    }
  }
}

extern "C" void kernel_launch(void* const* d_in, const int* in_sizes, int n_in,
                              void* d_out, int out_size, void* d_ws, size_t ws_size,
                              hipStream_t stream) {
  const float* x   = (const float*)d_in[0];
  const float* Wf  = (const float*)d_in[1];
  const float* bf_ = (const float*)d_in[2];
  const float* Wi  = (const float*)d_in[3];
  const float* bi_ = (const float*)d_in[4];
  const float* Wo  = (const float*)d_in[5];
  const float* bo_ = (const float*)d_in[6];
  const float* Wc  = (const float*)d_in[7];
  const float* bc_ = (const float*)d_in[8];
  float* out = (float*)d_out;

  const size_t hseq_bytes  = (size_t)T_ * 65536;          // 32 MiB packed chunks
  const size_t flags_bytes = (size_t)T_ * 512 * 4;        // 1 MiB per-wave flags
  const size_t xb_bytes    = (size_t)T_ * B_ * I_ * 2;    // 32 MiB
  const bool has_hseq = ws_size >= hseq_bytes + flags_bytes;
  const bool has_xb   = ws_size >= hseq_bytes + flags_bytes + xb_bytes;

  if (has_hseq) {
    char* hseqp        = (char*)d_ws;
    unsigned* flags    = (unsigned*)((char*)d_ws + hseq_bytes);
    unsigned short* xb = (unsigned short*)((char*)d_ws + hseq_bytes + flags_bytes);

    // only flags need re-arming each call (graph-replay safe); hseqp content
    // is gated by flags so its initial bytes are irrelevant.
    (void)hipMemsetAsync(flags, 0, flags_bytes, stream);

    if (has_xb) {
      const int total_vec = T_ * B_ * I_ / 4;
      convert_x_kernel<<<dim3(total_vec / 256), dim3(256), 0, stream>>>(x, xb);
      lstm_kernel<true><<<dim3(NB), dim3(NTHR), 0, stream>>>(
          xb, x, Wf, Wi, Wo, Wc, bf_, bi_, bo_, bc_, out, hseqp, flags);
    } else {
      lstm_kernel<false><<<dim3(NB), dim3(NTHR), 0, stream>>>(
          xb, x, Wf, Wi, Wo, Wc, bf_, bi_, bo_, bc_, out, hseqp, flags);
    }
  } else {
    unsigned short* hbuf = (unsigned short*)d_ws;
    (void)hipMemsetAsync(hbuf, 0, (size_t)2 * BH * 2, stream);
    for (int t = 0; t < T_; ++t)
      lstm_step_fallback_kernel<<<dim3(NB), dim3(128), 0, stream>>>(
          t, x, Wf, Wi, Wo, Wc, bf_, bi_, bo_, bc_, out, hbuf);
  }
}